// Round 1
// baseline (172.976 us; speedup 1.0000x reference)
//
#include <hip/hip_runtime.h>
#include <hip/hip_bf16.h>
#include <cstdint>

#define BATCH   32
#define NVARS   16
#define SAMPLES 4096
#define EDIM    128
#define WSZ     32
#define NTOK    1016          // (4096-32)/4
#define KDIM    4096          // WSZ*EDIM

typedef __bf16 bf8_t __attribute__((ext_vector_type(8)));
typedef float  f4_t  __attribute__((ext_vector_type(4)));

__device__ __forceinline__ void gload_lds16(const void* g, void* l) {
  __builtin_amdgcn_global_load_lds(
      (const __attribute__((address_space(1))) unsigned int*)g,
      (__attribute__((address_space(3))) unsigned int*)l, 16, 0, 0);
}

// ---------------------------------------------------------------------------
// Stage 1: enc[b][s][d] = floor(sum_v x[b][v][s]*W_sample[v][d] + b_sample[d])
// stored as bf16 (integers |v|<256 -> exact; truncation cast is exact).
// Thread: 8 consecutive d's -> one 16B store. W slice lives in registers.
// ---------------------------------------------------------------------------
__global__ __launch_bounds__(256) void encode_kernel(
    const float* __restrict__ x, const float* __restrict__ Ws,
    const float* __restrict__ bs, __hip_bfloat16* __restrict__ enc)
{
  int tid = threadIdx.x;
  int b   = blockIdx.x >> 6;          // 64 s-chunks per batch
  int s0  = (blockIdx.x & 63) << 6;   // 64 samples per block
  int d0  = (tid & 15) * 8;
  int sl  = tid >> 4;                 // 0..15

  float w[NVARS][8];
#pragma unroll
  for (int v = 0; v < NVARS; ++v) {
    float4 w0 = *(const float4*)&Ws[v * EDIM + d0];
    float4 w1 = *(const float4*)&Ws[v * EDIM + d0 + 4];
    w[v][0] = w0.x; w[v][1] = w0.y; w[v][2] = w0.z; w[v][3] = w0.w;
    w[v][4] = w1.x; w[v][5] = w1.y; w[v][6] = w1.z; w[v][7] = w1.w;
  }
  float bias[8];
  {
    float4 b0 = *(const float4*)&bs[d0];
    float4 b1 = *(const float4*)&bs[d0 + 4];
    bias[0] = b0.x; bias[1] = b0.y; bias[2] = b0.z; bias[3] = b0.w;
    bias[4] = b1.x; bias[5] = b1.y; bias[6] = b1.z; bias[7] = b1.w;
  }
  const float* xb = x + (size_t)b * NVARS * SAMPLES;
#pragma unroll
  for (int pass = 0; pass < 4; ++pass) {
    int s = s0 + pass * 16 + sl;
    float acc[8];
#pragma unroll
    for (int j = 0; j < 8; ++j) acc[j] = bias[j];
#pragma unroll
    for (int v = 0; v < NVARS; ++v) {
      float xv = xb[v * SAMPLES + s];
#pragma unroll
      for (int j = 0; j < 8; ++j) acc[j] += xv * w[v][j];
    }
    union { unsigned short u[8]; uint4 q; } pk;
#pragma unroll
    for (int j = 0; j < 8; ++j)
      pk.u[j] = (unsigned short)(__float_as_uint(floorf(acc[j])) >> 16);
    *(uint4*)((__hip_bfloat16*)enc + ((size_t)b * SAMPLES + s) * EDIM + d0) = pk.q;
  }
}

// ---------------------------------------------------------------------------
// W_patch [K=4096][N=128] fp32  ->  Wt [N=128][K=4096] bf16 (RNE cast).
// k-contiguous rows so B-fragments are 16B LDS reads in the GEMM.
// ---------------------------------------------------------------------------
__global__ __launch_bounds__(256) void twp_kernel(
    const float* __restrict__ Wp, __hip_bfloat16* __restrict__ Wt)
{
  __shared__ float t[32][33];
  int k0 = blockIdx.x * 32;
  int n0 = blockIdx.y * 32;
  int tx = threadIdx.x, ty = threadIdx.y;
#pragma unroll
  for (int j = 0; j < 4; ++j)
    t[ty + j * 8][tx] = Wp[(size_t)(k0 + ty + j * 8) * EDIM + n0 + tx];
  __syncthreads();
#pragma unroll
  for (int j = 0; j < 4; ++j)
    Wt[(size_t)(n0 + ty + j * 8) * KDIM + k0 + tx] =
        __float2bfloat16(t[tx][ty + j * 8]);
}

// ---------------------------------------------------------------------------
// Stage 2: tokens[b][t][n] = floor( sum_{w,e} enc[b][t*4+w][e]*Wp[w*128+e][n]
//                                   + b_patch[n] )
// GEMM M=32512 N=128 K=4096, bf16 MFMA 16x16x32, m97 structure:
// BM=BN=128 BK=32, 4 waves, wave tile 64x64 (4x4 frags),
// global_load_lds width-16 staging, A gathered from enc on the fly.
// ---------------------------------------------------------------------------
__global__ __launch_bounds__(256) void gemm_kernel(
    const __hip_bfloat16* __restrict__ enc,
    const __hip_bfloat16* __restrict__ Wt,
    const float* __restrict__ bp,
    float* __restrict__ out)
{
  __shared__ __align__(16) __hip_bfloat16 sA[128 * 32];  // [m][k], 64B rows
  __shared__ __align__(16) __hip_bfloat16 sB[128 * 32];  // [n][k], 64B rows

  int tid  = threadIdx.x;
  int lane = tid & 63;
  int wv   = tid >> 6;               // wave 0..3
  int b    = blockIdx.x >> 3;        // 8 m-tiles per batch
  int t0   = (blockIdx.x & 7) << 7;  // token-tile origin
  int wm   = (wv >> 1) << 6;         // wave row offset (0/64)
  int wn   = (wv & 1) << 6;          // wave col offset (0/64)
  int quad = lane >> 4;
  int l15  = lane & 15;

  const __hip_bfloat16* encb = enc + (size_t)b * SAMPLES * EDIM;

  f4_t acc[4][4];
  f4_t zero = {0.f, 0.f, 0.f, 0.f};
#pragma unroll
  for (int i = 0; i < 4; ++i)
#pragma unroll
    for (int j = 0; j < 4; ++j) acc[i][j] = zero;

  int srow0 = wv * 32;               // this wave stages rows srow0..srow0+31
  int rlane = lane >> 2;             // 0..15 : row within a 16-row issue
  int blane = (lane & 3) * 8;        // element offset (16B chunk) within row

  for (int kb = 0; kb < 128; ++kb) {
    int k0 = kb << 5;
    int w  = kb >> 2;                // window offset 0..31
    int e0 = (kb & 3) << 5;          // embed offset 0/32/64/96
#pragma unroll
    for (int q = 0; q < 2; ++q) {    // A: 16 rows per issue
      int r = srow0 + q * 16 + rlane;
      int s = (t0 + r) * 4 + w;
      s = min(s, SAMPLES - 1);       // clamp padding rows (t >= NTOK)
      gload_lds16(encb + (size_t)s * EDIM + e0 + blane,
                  &sA[(srow0 + q * 16) * 32]);
    }
#pragma unroll
    for (int q = 0; q < 2; ++q) {    // B: 16 rows per issue
      int n = srow0 + q * 16 + rlane;
      gload_lds16(Wt + (size_t)n * KDIM + k0 + blane,
                  &sB[(srow0 + q * 16) * 32]);
    }
    __syncthreads();                 // drains vmcnt -> LDS tiles valid

    const bf8_t* pA = (const bf8_t*)sA;
    const bf8_t* pB = (const bf8_t*)sB;
    bf8_t af[4], bfr[4];
#pragma unroll
    for (int i = 0; i < 4; ++i) af[i]  = pA[(wm + i * 16 + l15) * 4 + quad];
#pragma unroll
    for (int i = 0; i < 4; ++i) bfr[i] = pB[(wn + i * 16 + l15) * 4 + quad];
#pragma unroll
    for (int mi = 0; mi < 4; ++mi)
#pragma unroll
      for (int ni = 0; ni < 4; ++ni)
        acc[mi][ni] = __builtin_amdgcn_mfma_f32_16x16x32_bf16(
            af[mi], bfr[ni], acc[mi][ni], 0, 0, 0);
    __syncthreads();                 // protect LDS before next staging
  }

  // epilogue: C/D layout col=lane&15, row=quad*4+reg (m89/m91-verified)
  float bias[4];
#pragma unroll
  for (int ni = 0; ni < 4; ++ni) bias[ni] = bp[wn + ni * 16 + l15];
#pragma unroll
  for (int mi = 0; mi < 4; ++mi)
#pragma unroll
    for (int ni = 0; ni < 4; ++ni)
#pragma unroll
      for (int r = 0; r < 4; ++r) {
        int t = t0 + wm + mi * 16 + quad * 4 + r;
        if (t < NTOK) {
          int n = wn + ni * 16 + l15;
          out[((size_t)b * NTOK + t) * EDIM + n] =
              floorf(acc[mi][ni][r] + bias[ni]);
        }
      }
}

// ---------------------------------------------------------------------------
extern "C" void kernel_launch(void* const* d_in, const int* in_sizes, int n_in,
                              void* d_out, int out_size, void* d_ws, size_t ws_size,
                              hipStream_t stream) {
  const float* x  = (const float*)d_in[0];
  const float* Ws = (const float*)d_in[1];
  const float* bs = (const float*)d_in[2];
  const float* Wp = (const float*)d_in[3];
  const float* bp = (const float*)d_in[4];
  float* out = (float*)d_out;

  // workspace layout: enc bf16 [32][4096][128] (32 MB) | Wt bf16 [128][4096] (1 MB)
  __hip_bfloat16* enc = (__hip_bfloat16*)d_ws;
  __hip_bfloat16* Wt  = (__hip_bfloat16*)((char*)d_ws +
                        (size_t)BATCH * SAMPLES * EDIM * sizeof(__hip_bfloat16));

  encode_kernel<<<BATCH * (SAMPLES / 64), 256, 0, stream>>>(x, Ws, bs, enc);
  twp_kernel<<<dim3(KDIM / 32, EDIM / 32), dim3(32, 8), 0, stream>>>(Wp, Wt);
  gemm_kernel<<<BATCH * 8, 256, 0, stream>>>(enc, Wt, bp, out);
}

// Round 2
// 168.154 us; speedup vs baseline: 1.0287x; 1.0287x over previous
//
#include <hip/hip_runtime.h>
#include <hip/hip_bf16.h>
#include <cstdint>

#define BATCH   32
#define NVARS   16
#define SAMPLES 4096
#define EDIM    128
#define WSZ     32
#define NTOK    1016          // (4096-32)/4
#define KDIM    4096          // WSZ*EDIM

typedef __bf16 bf8_t __attribute__((ext_vector_type(8)));
typedef float  f4_t  __attribute__((ext_vector_type(4)));

__device__ __forceinline__ void gload_lds16(const void* g, void* l) {
  __builtin_amdgcn_global_load_lds(
      (const __attribute__((address_space(1))) unsigned int*)g,
      (__attribute__((address_space(3))) unsigned int*)l, 16, 0, 0);
}

// ---------------------------------------------------------------------------
// Stage 1: enc[b][s][d] = floor(sum_v x[b][v][s]*W_sample[v][d] + b_sample[d])
// stored as bf16 (small integers -> exact; truncation cast is exact).
// ---------------------------------------------------------------------------
__global__ __launch_bounds__(256) void encode_kernel(
    const float* __restrict__ x, const float* __restrict__ Ws,
    const float* __restrict__ bs, __hip_bfloat16* __restrict__ enc)
{
  int tid = threadIdx.x;
  int b   = blockIdx.x >> 6;
  int s0  = (blockIdx.x & 63) << 6;
  int d0  = (tid & 15) * 8;
  int sl  = tid >> 4;

  float w[NVARS][8];
#pragma unroll
  for (int v = 0; v < NVARS; ++v) {
    float4 w0 = *(const float4*)&Ws[v * EDIM + d0];
    float4 w1 = *(const float4*)&Ws[v * EDIM + d0 + 4];
    w[v][0] = w0.x; w[v][1] = w0.y; w[v][2] = w0.z; w[v][3] = w0.w;
    w[v][4] = w1.x; w[v][5] = w1.y; w[v][6] = w1.z; w[v][7] = w1.w;
  }
  float bias[8];
  {
    float4 b0 = *(const float4*)&bs[d0];
    float4 b1 = *(const float4*)&bs[d0 + 4];
    bias[0] = b0.x; bias[1] = b0.y; bias[2] = b0.z; bias[3] = b0.w;
    bias[4] = b1.x; bias[5] = b1.y; bias[6] = b1.z; bias[7] = b1.w;
  }
  const float* xb = x + (size_t)b * NVARS * SAMPLES;
#pragma unroll
  for (int pass = 0; pass < 4; ++pass) {
    int s = s0 + pass * 16 + sl;
    float acc[8];
#pragma unroll
    for (int j = 0; j < 8; ++j) acc[j] = bias[j];
#pragma unroll
    for (int v = 0; v < NVARS; ++v) {
      float xv = xb[v * SAMPLES + s];
#pragma unroll
      for (int j = 0; j < 8; ++j) acc[j] += xv * w[v][j];
    }
    union { unsigned short u[8]; uint4 q; } pk;
#pragma unroll
    for (int j = 0; j < 8; ++j)
      pk.u[j] = (unsigned short)(__float_as_uint(floorf(acc[j])) >> 16);
    *(uint4*)((__hip_bfloat16*)enc + ((size_t)b * SAMPLES + s) * EDIM + d0) = pk.q;
  }
}

// ---------------------------------------------------------------------------
// W_patch [K=4096][N=128] fp32 -> Wt [N=128][K=4096] bf16 (RNE).
// ---------------------------------------------------------------------------
__global__ __launch_bounds__(256) void twp_kernel(
    const float* __restrict__ Wp, __hip_bfloat16* __restrict__ Wt)
{
  __shared__ float t[32][33];
  int k0 = blockIdx.x * 32;
  int n0 = blockIdx.y * 32;
  int tx = threadIdx.x, ty = threadIdx.y;
#pragma unroll
  for (int j = 0; j < 4; ++j)
    t[ty + j * 8][tx] = Wp[(size_t)(k0 + ty + j * 8) * EDIM + n0 + tx];
  __syncthreads();
#pragma unroll
  for (int j = 0; j < 4; ++j)
    Wt[(size_t)(n0 + ty + j * 8) * KDIM + k0 + tx] =
        __float2bfloat16(t[tx][ty + j * 8]);
}

// ---------------------------------------------------------------------------
// Stage 2 GEMM: M=32512 N=128 K=4096, bf16 MFMA 16x16x32.
// BM=128 BN=64 BK=32, 512 blocks (2/CU), 4 waves, wave tile 64x32.
// Double-buffered LDS, ONE barrier/iter (prefetch issued post-barrier).
// Chunk swizzle phys=(c+(row>>1))&3 -> conflict-free ds_read_b128.
// Blocks b and b+256 share the A-window and land on the same XCD (256%8==0).
// ---------------------------------------------------------------------------
__global__ __launch_bounds__(256) void gemm_kernel(
    const __hip_bfloat16* __restrict__ enc,
    const __hip_bfloat16* __restrict__ Wt,
    const float* __restrict__ bp,
    float* __restrict__ out)
{
  __shared__ __align__(16) __hip_bfloat16 sA[2][128 * 32];  // [m][k] 64B rows
  __shared__ __align__(16) __hip_bfloat16 sB[2][64 * 32];   // [n][k] 64B rows

  int tid  = threadIdx.x;
  int lane = tid & 63;
  int wv   = tid >> 6;
  int bm   = blockIdx.x & 255;
  int b    = bm >> 3;
  int t0   = (bm & 7) << 7;          // 128 tokens per m-tile
  int n0   = (blockIdx.x >> 8) << 6; // 0 or 64
  int wm   = (wv >> 1) << 6;         // 0/64
  int wn   = (wv & 1) << 5;          // 0/32
  int quad = lane >> 4;
  int l15  = lane & 15;

  const __hip_bfloat16* encb = enc + (size_t)b * SAMPLES * EDIM;

  // staging lane roles
  int rlane = lane >> 2;                       // row within 16-row issue
  int p     = lane & 3;                        // physical 16B chunk slot
  int c     = (p - (rlane >> 1)) & 3;          // logical chunk (swizzle)
  int coff  = c * 8;                           // element offset

  f4_t acc[4][2];
  f4_t zero = {0.f, 0.f, 0.f, 0.f};
#pragma unroll
  for (int i = 0; i < 4; ++i)
#pragma unroll
    for (int j = 0; j < 2; ++j) acc[i][j] = zero;

  auto stage = [&](int kb, int buf) {
    int k0 = kb << 5;
    int w  = kb >> 2;
    int e0 = (kb & 3) << 5;
#pragma unroll
    for (int q = 0; q < 2; ++q) {              // A: 32 rows per wave
      int rowb = wv * 32 + q * 16;
      int s = (t0 + rowb + rlane) * 4 + w;
      s = min(s, SAMPLES - 1);
      gload_lds16(encb + (size_t)s * EDIM + e0 + coff, &sA[buf][rowb * 32]);
    }
    {                                          // B: 16 rows per wave
      int rowb = wv * 16;
      int n = n0 + rowb + rlane;
      gload_lds16(Wt + (size_t)n * KDIM + k0 + coff, &sB[buf][rowb * 32]);
    }
  };

  stage(0, 0);
  int cur = 0;
  int swz = (quad + (l15 >> 1)) & 3;           // physical chunk at read time

  for (int kb = 0; kb < 128; ++kb) {
    __syncthreads();                           // drains vmcnt -> buf[cur] valid
    if (kb < 127) stage(kb + 1, cur ^ 1);      // prefetch flies during compute

    const bf8_t* pA = (const bf8_t*)sA[cur];
    const bf8_t* pB = (const bf8_t*)sB[cur];
    bf8_t af[4], bfr[2];
#pragma unroll
    for (int i = 0; i < 4; ++i) af[i]  = pA[(wm + i * 16 + l15) * 4 + swz];
#pragma unroll
    for (int j = 0; j < 2; ++j) bfr[j] = pB[(wn + j * 16 + l15) * 4 + swz];
#pragma unroll
    for (int mi = 0; mi < 4; ++mi)
#pragma unroll
      for (int ni = 0; ni < 2; ++ni)
        acc[mi][ni] = __builtin_amdgcn_mfma_f32_16x16x32_bf16(
            af[mi], bfr[ni], acc[mi][ni], 0, 0, 0);
    cur ^= 1;
  }

  // epilogue: C/D layout col=lane&15, row=quad*4+reg
  float bias[2];
#pragma unroll
  for (int ni = 0; ni < 2; ++ni) bias[ni] = bp[n0 + wn + ni * 16 + l15];
#pragma unroll
  for (int mi = 0; mi < 4; ++mi)
#pragma unroll
    for (int ni = 0; ni < 2; ++ni)
#pragma unroll
      for (int r = 0; r < 4; ++r) {
        int t = t0 + wm + mi * 16 + quad * 4 + r;
        if (t < NTOK) {
          int n = n0 + wn + ni * 16 + l15;
          out[((size_t)b * NTOK + t) * EDIM + n] =
              floorf(acc[mi][ni][r] + bias[ni]);
        }
      }
}

// ---------------------------------------------------------------------------
extern "C" void kernel_launch(void* const* d_in, const int* in_sizes, int n_in,
                              void* d_out, int out_size, void* d_ws, size_t ws_size,
                              hipStream_t stream) {
  const float* x  = (const float*)d_in[0];
  const float* Ws = (const float*)d_in[1];
  const float* bs = (const float*)d_in[2];
  const float* Wp = (const float*)d_in[3];
  const float* bp = (const float*)d_in[4];
  float* out = (float*)d_out;

  __hip_bfloat16* enc = (__hip_bfloat16*)d_ws;
  __hip_bfloat16* Wt  = (__hip_bfloat16*)((char*)d_ws +
                        (size_t)BATCH * SAMPLES * EDIM * sizeof(__hip_bfloat16));

  encode_kernel<<<BATCH * (SAMPLES / 64), 256, 0, stream>>>(x, Ws, bs, enc);
  twp_kernel<<<dim3(KDIM / 32, EDIM / 32), dim3(32, 8), 0, stream>>>(Wp, Wt);
  gemm_kernel<<<BATCH * 16, 256, 0, stream>>>(enc, Wt, bp, out);
}

// Round 3
// 166.218 us; speedup vs baseline: 1.0407x; 1.0117x over previous
//
#include <hip/hip_runtime.h>
#include <hip/hip_bf16.h>
#include <cstdint>

#define BATCH   32
#define NVARS   16
#define SAMPLES 4096
#define EDIM    128
#define NTOK    1016          // (4096-32)/4
#define KDIM    4096          // WSZ*EDIM

typedef __bf16 bf8_t __attribute__((ext_vector_type(8)));
typedef float  f4_t  __attribute__((ext_vector_type(4)));

__device__ __forceinline__ void gload_lds16(const void* g, void* l) {
  __builtin_amdgcn_global_load_lds(
      (const __attribute__((address_space(1))) unsigned int*)g,
      (__attribute__((address_space(3))) unsigned int*)l, 16, 0, 0);
}

// ---------------------------------------------------------------------------
// Stage 1: enc[b][s][d] = floor(sum_v x[b][v][s]*W_sample[v][d] + b_sample[d])
// v2: x staged through LDS with fully-coalesced float4 loads; W slice is only
// 64 VGPRs (16v x 4d) -> no spill, ~4 waves/SIMD. bf16 store exact (ints).
// ---------------------------------------------------------------------------
__global__ __launch_bounds__(256) void encode_kernel(
    const float* __restrict__ x, const float* __restrict__ Ws,
    const float* __restrict__ bs, __hip_bfloat16* __restrict__ enc)
{
  __shared__ float xs[NVARS][256];
  int tid = threadIdx.x;
  int b   = blockIdx.x >> 4;          // 16 s-chunks of 256 per batch
  int s0  = (blockIdx.x & 15) << 8;

  const float* xb = x + (size_t)b * NVARS * SAMPLES + s0;
  {
    int col = (tid & 63) << 2;
    int v0  = tid >> 6;
#pragma unroll
    for (int j = 0; j < 4; ++j) {
      int v = v0 + j * 4;
      float4 t = *(const float4*)(xb + (size_t)v * SAMPLES + col);
      *(float4*)&xs[v][col] = t;
    }
  }

  int d0 = (tid & 31) * 4;
  int sl = tid >> 5;                  // 0..7
  float w[NVARS][4];
#pragma unroll
  for (int v = 0; v < NVARS; ++v) {
    float4 t = *(const float4*)&Ws[v * EDIM + d0];
    w[v][0] = t.x; w[v][1] = t.y; w[v][2] = t.z; w[v][3] = t.w;
  }
  float4 bias = *(const float4*)&bs[d0];

  __syncthreads();

  __hip_bfloat16* eb = enc + ((size_t)b * SAMPLES + s0) * EDIM + d0;
#pragma unroll 4
  for (int pass = 0; pass < 32; ++pass) {
    int s = pass * 8 + sl;
    float a0 = bias.x, a1 = bias.y, a2 = bias.z, a3 = bias.w;
#pragma unroll
    for (int v = 0; v < NVARS; ++v) {
      float xv = xs[v][s];            // 32-lane broadcast read
      a0 += xv * w[v][0]; a1 += xv * w[v][1];
      a2 += xv * w[v][2]; a3 += xv * w[v][3];
    }
    union { unsigned short u[4]; uint2 qq; } pk;
    pk.u[0] = (unsigned short)(__float_as_uint(floorf(a0)) >> 16);
    pk.u[1] = (unsigned short)(__float_as_uint(floorf(a1)) >> 16);
    pk.u[2] = (unsigned short)(__float_as_uint(floorf(a2)) >> 16);
    pk.u[3] = (unsigned short)(__float_as_uint(floorf(a3)) >> 16);
    *(uint2*)(eb + (size_t)s * EDIM) = pk.qq;
  }
}

// ---------------------------------------------------------------------------
// W_patch [K=4096][N=128] fp32 -> Wt [N=128][K=4096] bf16 (RNE).
// ---------------------------------------------------------------------------
__global__ __launch_bounds__(256) void twp_kernel(
    const float* __restrict__ Wp, __hip_bfloat16* __restrict__ Wt)
{
  __shared__ float t[32][33];
  int k0 = blockIdx.x * 32;
  int n0 = blockIdx.y * 32;
  int tx = threadIdx.x, ty = threadIdx.y;
#pragma unroll
  for (int j = 0; j < 4; ++j)
    t[ty + j * 8][tx] = Wp[(size_t)(k0 + ty + j * 8) * EDIM + n0 + tx];
  __syncthreads();
#pragma unroll
  for (int j = 0; j < 4; ++j)
    Wt[(size_t)(n0 + ty + j * 8) * KDIM + k0 + tx] =
        __float2bfloat16(t[tx][ty + j * 8]);
}

// ---------------------------------------------------------------------------
// Stage 2 GEMM: M=32512 N=128 K=4096, bf16 MFMA 16x16x32.
// BM=128 BN=64 BK=32, 512 blocks (2/CU), wave tile 64x32.
// 4-buffer LDS ring, prefetch distance 3, raw s_barrier + s_waitcnt vmcnt(6)
// (never 0 in steady state) -> load groups get ~3 iterations to fly.
// Linear kb addressing: A addr = (t0+row)*512 + kb*32 (window algebra folds).
// XCD swizzle: blockIdx%8 == batch%8 -> n-pair blocks share L2 for A.
// ---------------------------------------------------------------------------
__global__ __launch_bounds__(256) void gemm_kernel(
    const __hip_bfloat16* __restrict__ enc,
    const __hip_bfloat16* __restrict__ Wt,
    const float* __restrict__ bp,
    float* __restrict__ out)
{
  __shared__ __align__(16) __hip_bfloat16 sA[4][128 * 32];  // 32 KB
  __shared__ __align__(16) __hip_bfloat16 sB[4][64 * 32];   // 16 KB

  int tid  = threadIdx.x;
  int lane = tid & 63;
  int wv   = tid >> 6;
  int pb   = blockIdx.x;
  int qq   = pb >> 3;                 // 0..63
  int b    = (pb & 7) | ((qq >> 4) << 3);
  int t0   = ((qq >> 1) & 7) << 7;
  int n0   = (qq & 1) << 6;
  int wm   = (wv >> 1) << 6;          // 0/64
  int wn   = (wv & 1) << 5;           // 0/32
  int quad = lane >> 4;
  int l15  = lane & 15;

  // staging lane roles (chunk swizzle phys=(c+(row>>1))&3, conflict-free)
  int rlane = lane >> 2;              // row within 16-row issue
  int pc    = lane & 3;               // physical 16B chunk slot
  int c     = (pc - (rlane >> 1)) & 3;

  const __hip_bfloat16* a0p = enc + (size_t)b * SAMPLES * EDIM
                            + (size_t)(t0 + wv * 32 + rlane) * 512 + c * 8;
  const __hip_bfloat16* a1p = a0p + 16 * 512;
  const __hip_bfloat16* b0p = Wt + (size_t)(n0 + wv * 16 + rlane) * KDIM + c * 8;

  f4_t acc[4][2];
  f4_t zero = {0.f, 0.f, 0.f, 0.f};
#pragma unroll
  for (int i = 0; i < 4; ++i)
#pragma unroll
    for (int j = 0; j < 2; ++j) acc[i][j] = zero;

  auto stage = [&](int kb, int buf) {
    int ko = kb * 32;                 // elements; 64 B per iter
    gload_lds16(a0p + ko, &sA[buf][(wv * 32) * 32]);
    gload_lds16(a1p + ko, &sA[buf][(wv * 32 + 16) * 32]);
    gload_lds16(b0p + ko, &sB[buf][(wv * 16) * 32]);
  };

  int swz = (quad + (l15 >> 1)) & 3;
  auto compute = [&](int buf) {
    const bf8_t* pA = (const bf8_t*)sA[buf];
    const bf8_t* pB = (const bf8_t*)sB[buf];
    bf8_t af[4], bfr[2];
#pragma unroll
    for (int i = 0; i < 4; ++i) af[i]  = pA[(wm + i * 16 + l15) * 4 + swz];
#pragma unroll
    for (int j = 0; j < 2; ++j) bfr[j] = pB[(wn + j * 16 + l15) * 4 + swz];
#pragma unroll
    for (int mi = 0; mi < 4; ++mi)
#pragma unroll
      for (int ni = 0; ni < 2; ++ni)
        acc[mi][ni] = __builtin_amdgcn_mfma_f32_16x16x32_bf16(
            af[mi], bfr[ni], acc[mi][ni], 0, 0, 0);
  };

  stage(0, 0); stage(1, 1); stage(2, 2);        // 9 loads in flight

  for (int kb = 0; kb < 126; ++kb) {
    asm volatile("s_waitcnt vmcnt(6)" ::: "memory");  // oldest group landed
    __builtin_amdgcn_s_barrier();                     // raw: no vmcnt(0) drain
    if (kb < 125) stage(kb + 3, (kb + 3) & 3);        // refill to 9 in flight
    compute(kb & 3);
  }
  asm volatile("s_waitcnt vmcnt(3)" ::: "memory");
  __builtin_amdgcn_s_barrier();
  compute(126 & 3);
  asm volatile("s_waitcnt vmcnt(0)" ::: "memory");
  __builtin_amdgcn_s_barrier();
  compute(127 & 3);

  // epilogue: C/D layout col=lane&15, row=quad*4+reg
  float bias[2];
#pragma unroll
  for (int ni = 0; ni < 2; ++ni) bias[ni] = bp[n0 + wn + ni * 16 + l15];
#pragma unroll
  for (int mi = 0; mi < 4; ++mi)
#pragma unroll
    for (int ni = 0; ni < 2; ++ni)
#pragma unroll
      for (int r = 0; r < 4; ++r) {
        int t = t0 + wm + mi * 16 + quad * 4 + r;
        if (t < NTOK) {
          int n = n0 + wn + ni * 16 + l15;
          out[((size_t)b * NTOK + t) * EDIM + n] =
              floorf(acc[mi][ni][r] + bias[ni]);
        }
      }
}

// ---------------------------------------------------------------------------
extern "C" void kernel_launch(void* const* d_in, const int* in_sizes, int n_in,
                              void* d_out, int out_size, void* d_ws, size_t ws_size,
                              hipStream_t stream) {
  const float* x  = (const float*)d_in[0];
  const float* Ws = (const float*)d_in[1];
  const float* bs = (const float*)d_in[2];
  const float* Wp = (const float*)d_in[3];
  const float* bp = (const float*)d_in[4];
  float* out = (float*)d_out;

  __hip_bfloat16* enc = (__hip_bfloat16*)d_ws;
  __hip_bfloat16* Wt  = (__hip_bfloat16*)((char*)d_ws +
                        (size_t)BATCH * SAMPLES * EDIM * sizeof(__hip_bfloat16));

  encode_kernel<<<BATCH * (SAMPLES / 256), 256, 0, stream>>>(x, Ws, bs, enc);
  twp_kernel<<<dim3(KDIM / 32, EDIM / 32), dim3(32, 8), 0, stream>>>(Wp, Wt);
  gemm_kernel<<<BATCH * 16, 256, 0, stream>>>(enc, Wt, bp, out);
}